// Round 5
// baseline (2136.552 us; speedup 1.0000x reference)
//
#include <hip/hip_runtime.h>

typedef _Float16 f16;
typedef f16 f16x8 __attribute__((ext_vector_type(8)));
typedef float f32x4 __attribute__((ext_vector_type(4)));

#define BB 8
#define TT 16
#define NPIX 784
#define W28 28

__device__ __forceinline__ float sigm_(float x) { return 1.0f / (1.0f + __expf(-x)); }
__device__ __forceinline__ float tanh_(float x) { return 2.0f / (1.0f + __expf(-2.0f * x)) - 1.0f; }

// Implicit-GEMM 3x3 conv + fused LSTM pointwise epilogue.
// Block: 256 thr = 4 waves. Spatial tile = 4 rows x NF*4 cols (NF n-frags of
// 16 px). Wave wv owns m-rows [wv*HC, (wv+1)*HC); each A-frag global load
// feeds NF MFMAs (A-reuse = NF). Input staged to LDS in NCH chunks of KCH
// channels. MODE 0: conv_pre (write raw gates); MODE 1: L0 cell (adds
// precomputed gx); MODE 2: generic cell.
template<int CINT, int KCH, int HC, int MODE, int NF>
__global__ __launch_bounds__(256)
void cell_mfma(const f16* __restrict__ Apack,   // [4HC][9*CINT] k-contiguous
               const f16* __restrict__ in0, int split,
               const f16* __restrict__ in1,
               const f16* __restrict__ gxt, long gx_bstride,
               f16* __restrict__ gxout,
               const float* __restrict__ bx,
               const float* __restrict__ WpT,   // [pix][3][HC]
               float* __restrict__ cbuf,        // [b][pix][HC] f32
               f16* __restrict__ hout)          // [b][pix][HC] f16
{
    constexpr int CINTP = KCH + 8;
    constexpr int HALOW = NF * 4 + 2;
    constexpr int LOCS  = 6 * HALOW;
    constexpr int MBLK  = 4 * HC;
    constexpr int KTOT  = 9 * CINT;
    constexpr int NSUB  = HC / 16;
    constexpr int NCH   = CINT / KCH;
    constexpr int SB    = LOCS * CINTP * 2;
    constexpr int CBY   = MBLK * 17 * 4;
    constexpr int SMEMB = SB > CBY ? SB : CBY;
    __shared__ __align__(16) char smem[SMEMB];
    f16*   S = (f16*)smem;
    float* C = (float*)smem;

    constexpr int NXB = (NF == 4) ? 2 : 1;
    const int ty = blockIdx.x / NXB;
    const int X0 = (blockIdx.x % NXB) * 16;
    const int Y0 = ty * 4;
    const int b  = blockIdx.y;
    const int tid = threadIdx.x;
    const int lane = tid & 63, wv = tid >> 6;
    const int ln = lane & 15, quad = lane >> 4;
    const int sy = ln >> 2, sx = ln & 3;

    f32x4 acc[NSUB][NF] = {};
    const f16* abase = Apack + (long)(wv * HC + ln) * KTOT + quad * 8;

    for (int ch = 0; ch < NCH; ++ch) {
        __syncthreads();
        constexpr int VPL = KCH / 8;
        for (int it = tid; it < LOCS * VPL; it += 256) {
            int loc = it / VPL;
            int cc  = ch * KCH + (it - loc * VPL) * 8;
            int ly = loc / HALOW, lx = loc - ly * HALOW;
            int y = Y0 - 1 + ly, x = X0 - 1 + lx;
            f16x8 val = {};
            if (y >= 0 && y < W28 && x >= 0 && x < W28) {
                int pix = y * W28 + x;
                const f16* src = (cc < split)
                    ? in0 + ((long)b * NPIX + pix) * split + cc
                    : in1 + ((long)b * NPIX + pix) * (CINT - split) + (cc - split);
                val = *(const f16x8*)src;
            }
            *(f16x8*)&S[loc * CINTP + (it - loc * VPL) * 8] = val;
        }
        __syncthreads();

#pragma unroll
        for (int tap = 0; tap < 9; ++tap) {
            const int ky = tap / 3, kx = tap - ky * 3;
            const long aoff = (long)tap * CINT + ch * KCH;   // NO quad*8 here (it's in abase)
#pragma unroll
            for (int c0 = 0; c0 < KCH; c0 += 32) {
                f16x8 bf[NF];
#pragma unroll
                for (int f = 0; f < NF; ++f)
                    bf[f] = *(const f16x8*)&S[((sy + ky) * HALOW + sx + f * 4 + kx) * CINTP
                                              + c0 + quad * 8];
#pragma unroll
                for (int s = 0; s < NSUB; ++s) {
                    f16x8 af = *(const f16x8*)(abase + (long)s * 16 * KTOT + aoff + c0);
#pragma unroll
                    for (int f = 0; f < NF; ++f)
                        acc[s][f] = __builtin_amdgcn_mfma_f32_16x16x32_f16(af, bf[f], acc[s][f], 0, 0, 0);
                }
            }
        }
    }

    // ---- epilogue, one n-frag (16 px) at a time through LDS C ----
#pragma unroll
    for (int f = 0; f < NF; ++f) {
        const int xf = X0 + f * 4;
        if (xf >= W28) continue;          // block-uniform
        __syncthreads();
#pragma unroll
        for (int s = 0; s < NSUB; ++s) {
            int m = wv * HC + s * 16 + quad * 4;
#pragma unroll
            for (int r = 0; r < 4; ++r)
                C[(m + r) * 17 + ln] = acc[s][f][r];
        }
        __syncthreads();

        if constexpr (MODE == 0) {
#pragma unroll
            for (int it = 0; it < 16; ++it) {
                int idx = it * 256 + tid;
                int m = idx & (MBLK - 1), n = idx >> 8;   // MBLK==256 here
                int pix = (Y0 + (n >> 2)) * W28 + xf + (n & 3);
                gxout[((long)b * NPIX + pix) * 256 + m] = (f16)C[m * 17 + n];
            }
        } else {
            constexpr int PER = HC * 16 / 256;
#pragma unroll
            for (int it = 0; it < PER; ++it) {
                int idx = it * 256 + tid;
                int hc = idx % HC, n = idx / HC;
                int pix = (Y0 + (n >> 2)) * W28 + xf + (n & 3);
                float g0 = C[(0 * HC + hc) * 17 + n] + bx[0 * HC + hc];
                float g1 = C[(1 * HC + hc) * 17 + n] + bx[1 * HC + hc];
                float g2 = C[(2 * HC + hc) * 17 + n] + bx[2 * HC + hc];
                float g3 = C[(3 * HC + hc) * 17 + n] + bx[3 * HC + hc];
                if constexpr (MODE == 1) {
                    const f16* g = gxt + (long)b * gx_bstride + (long)pix * 256;
                    g0 += (float)g[0 * 64 + hc];
                    g1 += (float)g[1 * 64 + hc];
                    g2 += (float)g[2 * 64 + hc];
                    g3 += (float)g[3 * 64 + hc];
                }
                long ci = ((long)b * NPIX + pix) * HC + hc;
                const float* wpp = WpT + (long)pix * 3 * HC;
                float cp = cbuf[ci];
                float ig = sigm_(g0 + cp * wpp[0 * HC + hc]);
                float fg = sigm_(g1 + cp * wpp[1 * HC + hc]);
                float gg = tanh_(g2);
                float cn = fg * cp + ig * gg;
                float og = sigm_(g3 + cn * wpp[2 * HC + hc]);
                float hn = og * tanh_(cn);
                cbuf[ci] = cn;
                hout[ci] = (f16)hn;
            }
        }
    }
}

// Pack all conv weights to f16 [m][tap*CINT+cin] (k-contiguous, tap-major).
__global__ __launch_bounds__(256)
void pack_weights(const float* __restrict__ Wx0, const float* __restrict__ Wh0,
                  const float* __restrict__ Wx1, const float* __restrict__ Wh1,
                  const float* __restrict__ Wx2, const float* __restrict__ Wh2,
                  f16* __restrict__ A)
{
    const int NPRE = 256 * 1728, N0 = 256 * 576, N1 = 128 * 864, N2 = 256 * 864;
    int idx = blockIdx.x * 256 + threadIdx.x;
    if (idx >= NPRE + N0 + N1 + N2) return;
    float v;
    if (idx < NPRE) {
        int m = idx / 1728, k = idx % 1728, tap = k / 192, ci = k % 192;
        v = Wx0[(m * 192 + ci) * 9 + tap];
    } else if (idx < NPRE + N0) {
        int r = idx - NPRE; int m = r / 576, k = r % 576, tap = k / 64, ci = k % 64;
        v = Wh0[(m * 64 + ci) * 9 + tap];
    } else if (idx < NPRE + N0 + N1) {
        int r = idx - NPRE - N0; int m = r / 864, k = r % 864, tap = k / 96, ci = k % 96;
        v = (ci < 64) ? Wx1[(m * 64 + ci) * 9 + tap] : Wh1[(m * 32 + (ci - 64)) * 9 + tap];
    } else {
        int r = idx - NPRE - N0 - N1; int m = r / 864, k = r % 864, tap = k / 96, ci = k % 96;
        v = (ci < 32) ? Wx2[(m * 32 + ci) * 9 + tap] : Wh2[(m * 64 + (ci - 32)) * 9 + tap];
    }
    A[idx] = (f16)v;
}

// x (B*T,192,784) f32 -> xT (B*T,784,192) f16, LDS-bounced transpose.
__global__ __launch_bounds__(256)
void transpose_x(const float* __restrict__ x, f16* __restrict__ xT)
{
    __shared__ float T[16 * 200];
    const int bt = blockIdx.y, p0 = blockIdx.x * 16;
    const int tid = threadIdx.x;
    const float* xb = x + (long)bt * 192 * NPIX;
#pragma unroll
    for (int it = 0; it < 12; ++it) {
        int idx = it * 256 + tid;
        int c = idx >> 4, p = idx & 15;
        T[p * 200 + c] = xb[c * NPIX + p0 + p];
    }
    __syncthreads();
    f16* dst = xT + ((long)bt * NPIX + p0) * 192;
#pragma unroll
    for (int it = 0; it < 12; ++it) {
        int idx = it * 256 + tid;
        int p = idx / 192, c = idx - p * 192;
        dst[p * 192 + c] = (f16)T[p * 200 + c];
    }
}

// Wp (3,HC,784) -> WpT (784,3,HC), per layer.
__global__ __launch_bounds__(256)
void transpose_wp(const float* __restrict__ Wp0, const float* __restrict__ Wp1,
                  const float* __restrict__ Wp2,
                  float* __restrict__ T0, float* __restrict__ T1, float* __restrict__ T2)
{
    const int N0 = NPIX * 192, N1 = NPIX * 96, N2 = NPIX * 192;
    int idx = blockIdx.x * 256 + threadIdx.x;
    if (idx < N0) {
        int pix = idx / 192, r = idx % 192;
        T0[idx] = Wp0[r * NPIX + pix];
    } else if (idx < N0 + N1) {
        int i = idx - N0; int pix = i / 96, r = i % 96;
        T1[i] = Wp1[r * NPIX + pix];
    } else if (idx < N0 + N1 + N2) {
        int i = idx - N0 - N1; int pix = i / 192, r = i % 192;
        T2[i] = Wp2[r * NPIX + pix];
    }
}

// h2 history f16 [17][b][pix][64] (slot t+1) -> out f32 (B,T,64,28,28)
__global__ __launch_bounds__(256)
void reshape_out(const f16* __restrict__ h2buf, float* __restrict__ out)
{
    int idx = blockIdx.x * 256 + threadIdx.x;
    int pix = idx % NPIX; int r = idx / NPIX;
    int hc = r & 63; r >>= 6;
    int t = r & 15; int b = r >> 4;
    out[idx] = (float)h2buf[((((long)(t + 1) * BB + b) * NPIX) + pix) * 64 + hc];
}

extern "C" void kernel_launch(void* const* d_in, const int* in_sizes, int n_in,
                              void* d_out, int out_size, void* d_ws, size_t ws_size,
                              hipStream_t stream)
{
    const float* x   = (const float*)d_in[0];
    const float* Wx0 = (const float*)d_in[1];
    const float* bx0 = (const float*)d_in[2];
    const float* Wh0 = (const float*)d_in[3];
    const float* Wp0 = (const float*)d_in[4];
    const float* Wx1 = (const float*)d_in[5];
    const float* bx1 = (const float*)d_in[6];
    const float* Wh1 = (const float*)d_in[7];
    const float* Wp1 = (const float*)d_in[8];
    const float* Wx2 = (const float*)d_in[9];
    const float* bx2 = (const float*)d_in[10];
    const float* Wh2 = (const float*)d_in[11];
    const float* Wp2 = (const float*)d_in[12];
    (void)in_sizes; (void)n_in; (void)out_size; (void)ws_size;

    char* w = (char*)d_ws;
    f16* Apack = (f16*)w;                                   // 1,843,200 B
    f16* Apre  = Apack;
    f16* Ap0   = Apre + 256L * 1728;
    f16* Ap1   = Ap0  + 256L * 576;
    f16* Ap2   = Ap1  + 128L * 864;
    f16* xT    = (f16*)(w + 1843200);                       // 38,535,168 B
    f16* gx    = (f16*)(w + 40378368);                      // 51,380,224 B
    float* c0  = (float*)(w + 91758592);                    // 1,605,632 B
    float* c1  = c0 + (long)BB * NPIX * 64;                 //   802,816 B
    float* c2  = c1 + (long)BB * NPIX * 32;                 // 1,605,632 B
    f16* h0    = (f16*)(c2 + (long)BB * NPIX * 64);         // 2x  802,816 B
    f16* h1    = h0 + 2L * BB * NPIX * 64;                  // 2x  401,408 B
    f16* h2buf = h1 + 2L * BB * NPIX * 32;                  // 17x 802,816 B
    float* WpT0 = (float*)(w + 111828992);                  //   602,112 B
    float* WpT1 = WpT0 + (long)NPIX * 192;                  //   301,056 B
    float* WpT2 = WpT1 + (long)NPIX * 96;                   //   602,112 B

    // zero c0..h1 + h2 slot 0 (contiguous: 7,225,344 B from c0)
    hipMemsetAsync(c0, 0, (size_t)7225344, stream);

    pack_weights<<<3600, 256, 0, stream>>>(Wx0, Wh0, Wx1, Wh1, Wx2, Wh2, Apack);
    transpose_x<<<dim3(49, BB * TT), 256, 0, stream>>>(x, xT);
    transpose_wp<<<1470, 256, 0, stream>>>(Wp0, Wp1, Wp2, WpT0, WpT1, WpT2);

    // time-parallel layer-0 input conv for all B*T images (4x28 strips)
    cell_mfma<192, 96, 64, 0, 7><<<dim3(7, BB * TT), 256, 0, stream>>>(
        Apre, xT, 192, nullptr, nullptr, 0, gx,
        nullptr, nullptr, nullptr, nullptr);

    for (int t = 0; t < TT; ++t) {
        const int cur = t & 1, nxt = cur ^ 1;
        f16* h0c = h0 + (long)cur * BB * NPIX * 64;
        f16* h0n = h0 + (long)nxt * BB * NPIX * 64;
        f16* h1c = h1 + (long)cur * BB * NPIX * 32;
        f16* h1n = h1 + (long)nxt * BB * NPIX * 32;
        const f16* h2p = h2buf + (long)t * BB * NPIX * 64;
        f16* h2n = h2buf + (long)(t + 1) * BB * NPIX * 64;

        cell_mfma<64, 64, 64, 1, 4><<<dim3(14, BB), 256, 0, stream>>>(
            Ap0, h0c, 64, nullptr,
            gx + (long)t * NPIX * 256, (long)TT * NPIX * 256,
            nullptr, bx0, WpT0, c0, h0n);
        cell_mfma<96, 96, 32, 2, 4><<<dim3(14, BB), 256, 0, stream>>>(
            Ap1, h0n, 64, h1c, nullptr, 0, nullptr, bx1, WpT1, c1, h1n);
        cell_mfma<96, 96, 64, 2, 4><<<dim3(14, BB), 256, 0, stream>>>(
            Ap2, h1n, 32, h2p, nullptr, 0, nullptr, bx2, WpT2, c2, h2n);
    }

    reshape_out<<<25088, 256, 0, stream>>>(h2buf, (float*)d_out);
}

// Round 7
// 1011.161 us; speedup vs baseline: 2.1130x; 2.1130x over previous
//
#include <hip/hip_runtime.h>

typedef _Float16 f16;
typedef f16 f16x8 __attribute__((ext_vector_type(8)));
typedef float f32x4 __attribute__((ext_vector_type(4)));

#define BB 8
#define TT 16
#define NPIX 784
#define W28 28

__device__ __forceinline__ float sigm_(float x) { return 1.0f / (1.0f + __expf(-x)); }
__device__ __forceinline__ float tanh_(float x) { return 2.0f / (1.0f + __expf(-2.0f * x)) - 1.0f; }

// Implicit-GEMM 3x3 conv body + fused LSTM pointwise epilogue.
// NOINLINE: compiled once per instantiation (3 instantiations force-inlined
// into one kernel segfaulted clang-22). __shared__ lives inside so the
// outlined function keeps LDS addrspace; per-kernel LDS = sum over
// reachable instantiations (diag: 47.3 KB -> ~3 blocks/CU).
// 256 thr = 4 waves. Spatial tile = 4 rows x NF*4 cols. Block owns m-rows
// [mh*MH,(mh+1)*MH), MH = 4HC/MSP (MSP>1 only for MODE 0).
// MODE 0: conv_pre; MODE 1: L0 cell (+precomputed gx); MODE 2: generic cell.
template<int CINT, int KCH, int HC, int MODE, int NF, int MSP>
__device__ __attribute__((noinline)) void cell_body(
    int X0, int Y0, int mh, int b,
    const f16* __restrict__ Apack,   // [4HC][9*CINT] k-contiguous
    const f16* __restrict__ in0, int split,
    const f16* __restrict__ in1,
    const f16* __restrict__ gxt, long gx_bstride,
    f16* __restrict__ gxout,
    const float* __restrict__ bx,
    const float* __restrict__ WpT,   // [pix][3][HC]
    float* __restrict__ cbuf,        // [b][pix][HC] f32
    f16* __restrict__ hout)          // [b][pix][HC] f16
{
    constexpr int CINTP = KCH + 8;
    constexpr int HALOW = NF * 4 + 2;
    constexpr int LOCS  = 6 * HALOW;
    constexpr int MBLK  = 4 * HC;
    constexpr int MH    = MBLK / MSP;
    constexpr int KTOT  = 9 * CINT;
    constexpr int NSUB  = MH / 64;      // 16-row subtiles per wave
    constexpr int NCH   = CINT / KCH;
    constexpr int SB    = LOCS * CINTP * 2;
    constexpr int CBY   = MH * 17 * 4;
    constexpr int SMEMB = SB > CBY ? SB : CBY;
    __shared__ __align__(16) char smem[SMEMB];
    f16*   S = (f16*)smem;
    float* C = (float*)smem;

    const int tid = threadIdx.x;
    const int lane = tid & 63, wv = tid >> 6;
    const int ln = lane & 15, quad = lane >> 4;
    const int sy = ln >> 2, sx = ln & 3;

    f32x4 acc[NSUB][NF] = {};
    const f16* abase = Apack + (long)(mh * MH + wv * (MH / 4) + ln) * KTOT + quad * 8;

    for (int ch = 0; ch < NCH; ++ch) {
        __syncthreads();
        constexpr int VPL = KCH / 8;
        for (int it = tid; it < LOCS * VPL; it += 256) {
            int loc = it / VPL;
            int cc  = ch * KCH + (it - loc * VPL) * 8;
            int ly = loc / HALOW, lx = loc - ly * HALOW;
            int y = Y0 - 1 + ly, x = X0 - 1 + lx;
            f16x8 val = {};
            if (y >= 0 && y < W28 && x >= 0 && x < W28) {
                int pix = y * W28 + x;
                const f16* src = (cc < split)
                    ? in0 + ((long)b * NPIX + pix) * split + cc
                    : in1 + ((long)b * NPIX + pix) * (CINT - split) + (cc - split);
                val = *(const f16x8*)src;
            }
            *(f16x8*)&S[loc * CINTP + (it - loc * VPL) * 8] = val;
        }
        __syncthreads();

#pragma unroll
        for (int tap = 0; tap < 9; ++tap) {
            const int ky = tap / 3, kx = tap - ky * 3;
            const long aoff = (long)tap * CINT + ch * KCH;   // quad*8 lives in abase
#pragma unroll
            for (int c0 = 0; c0 < KCH; c0 += 32) {
                f16x8 bf[NF];
#pragma unroll
                for (int f = 0; f < NF; ++f)
                    bf[f] = *(const f16x8*)&S[((sy + ky) * HALOW + sx + f * 4 + kx) * CINTP
                                              + c0 + quad * 8];
#pragma unroll
                for (int s = 0; s < NSUB; ++s) {
                    f16x8 af = *(const f16x8*)(abase + (long)s * 16 * KTOT + aoff + c0);
#pragma unroll
                    for (int f = 0; f < NF; ++f)
                        acc[s][f] = __builtin_amdgcn_mfma_f32_16x16x32_f16(af, bf[f], acc[s][f], 0, 0, 0);
                }
            }
        }
    }

    // ---- epilogue, one n-frag (16 px) at a time through LDS C ----
#pragma unroll
    for (int f = 0; f < NF; ++f) {
        const int xf = X0 + f * 4;
        if (xf >= W28) continue;          // block-uniform
        __syncthreads();
#pragma unroll
        for (int s = 0; s < NSUB; ++s) {
            int m = wv * (MH / 4) + s * 16 + quad * 4;
#pragma unroll
            for (int r = 0; r < 4; ++r)
                C[(m + r) * 17 + ln] = acc[s][f][r];
        }
        __syncthreads();

        if constexpr (MODE == 0) {
            constexpr int PER = MH * 16 / 256;
#pragma unroll
            for (int it = 0; it < PER; ++it) {
                int idx = it * 256 + tid;
                int m = idx & (MH - 1), n = idx / MH;
                int pix = (Y0 + (n >> 2)) * W28 + xf + (n & 3);
                gxout[((long)b * NPIX + pix) * MBLK + mh * MH + m] = (f16)C[m * 17 + n];
            }
        } else {
            constexpr int PER = HC * 16 / 256;
#pragma unroll
            for (int it = 0; it < PER; ++it) {
                int idx = it * 256 + tid;
                int hc = idx % HC, n = idx / HC;
                int pix = (Y0 + (n >> 2)) * W28 + xf + (n & 3);
                float g0 = C[(0 * HC + hc) * 17 + n] + bx[0 * HC + hc];
                float g1 = C[(1 * HC + hc) * 17 + n] + bx[1 * HC + hc];
                float g2 = C[(2 * HC + hc) * 17 + n] + bx[2 * HC + hc];
                float g3 = C[(3 * HC + hc) * 17 + n] + bx[3 * HC + hc];
                if constexpr (MODE == 1) {
                    const f16* g = gxt + (long)b * gx_bstride + (long)pix * 256;
                    g0 += (float)g[0 * 64 + hc];
                    g1 += (float)g[1 * 64 + hc];
                    g2 += (float)g[2 * 64 + hc];
                    g3 += (float)g[3 * 64 + hc];
                }
                long ci = ((long)b * NPIX + pix) * HC + hc;
                const float* wpp = WpT + (long)pix * 3 * HC;
                float cp = cbuf[ci];
                float ig = sigm_(g0 + cp * wpp[0 * HC + hc]);
                float fg = sigm_(g1 + cp * wpp[1 * HC + hc]);
                float gg = tanh_(g2);
                float cn = fg * cp + ig * gg;
                float og = sigm_(g3 + cn * wpp[2 * HC + hc]);
                float hn = og * tanh_(cn);
                cbuf[ci] = cn;
                hout[ci] = (f16)hn;
            }
        }
    }
}

// Time-parallel layer-0 input conv: 4x28 strips, M split in 2 halves.
__global__ __launch_bounds__(256)
void conv_pre_kernel(const f16* __restrict__ xT, const f16* __restrict__ Apre,
                     f16* __restrict__ gx)
{
    const int mh = blockIdx.x & 1, ty = blockIdx.x >> 1;
    cell_body<192, 96, 64, 0, 7, 2>(0, ty * 4, mh, blockIdx.y,
        Apre, xT, 192, nullptr, nullptr, 0, gx, nullptr, nullptr, nullptr, nullptr);
}

// Diagonal-wavefront cell kernel: blockIdx.z = layer, t = d - layer.
// One launch per diagonal replaces 3 dependent cell launches.
__global__ __launch_bounds__(256)
void diag_kernel(int d,
                 const f16* __restrict__ Ap0, const f16* __restrict__ Ap1,
                 const f16* __restrict__ Ap2, const f16* __restrict__ gx,
                 const float* __restrict__ bx0, const float* __restrict__ bx1,
                 const float* __restrict__ bx2,
                 const float* __restrict__ WpT0, const float* __restrict__ WpT1,
                 const float* __restrict__ WpT2,
                 float* __restrict__ c0, float* __restrict__ c1,
                 float* __restrict__ c2,
                 f16* __restrict__ h0, f16* __restrict__ h1,
                 f16* __restrict__ h2buf)
{
    const int layer = blockIdx.z;
    const int t = d - layer;
    if (t < 0 || t >= TT) return;
    const int b = blockIdx.y;
    const int X0 = (blockIdx.x & 3) * 8, Y0 = (blockIdx.x >> 2) * 4;
    const long SZ0 = (long)BB * NPIX * 64;
    const long SZ1 = (long)BB * NPIX * 32;
    const int cur = t & 1, nxt = cur ^ 1;

    if (layer == 0) {
        cell_body<64, 64, 64, 1, 2, 1>(X0, Y0, 0, b, Ap0,
            h0 + cur * SZ0, 64, nullptr,
            gx + (long)t * NPIX * 256, (long)TT * NPIX * 256, nullptr,
            bx0, WpT0, c0, h0 + nxt * SZ0);
    } else if (layer == 1) {
        cell_body<96, 96, 32, 2, 2, 1>(X0, Y0, 0, b, Ap1,
            h0 + nxt * SZ0, 64, h1 + cur * SZ1,
            nullptr, 0, nullptr, bx1, WpT1, c1, h1 + nxt * SZ1);
    } else {
        cell_body<96, 96, 64, 2, 2, 1>(X0, Y0, 0, b, Ap2,
            h1 + nxt * SZ1, 32, h2buf + (long)t * SZ0,
            nullptr, 0, nullptr, bx2, WpT2, c2, h2buf + (long)(t + 1) * SZ0);
    }
}

// Pack all conv weights to f16 [m][tap*CINT+cin] (k-contiguous, tap-major).
__global__ __launch_bounds__(256)
void pack_weights(const float* __restrict__ Wx0, const float* __restrict__ Wh0,
                  const float* __restrict__ Wx1, const float* __restrict__ Wh1,
                  const float* __restrict__ Wx2, const float* __restrict__ Wh2,
                  f16* __restrict__ A)
{
    const int NPRE = 256 * 1728, N0 = 256 * 576, N1 = 128 * 864, N2 = 256 * 864;
    int idx = blockIdx.x * 256 + threadIdx.x;
    if (idx >= NPRE + N0 + N1 + N2) return;
    float v;
    if (idx < NPRE) {
        int m = idx / 1728, k = idx % 1728, tap = k / 192, ci = k % 192;
        v = Wx0[(m * 192 + ci) * 9 + tap];
    } else if (idx < NPRE + N0) {
        int r = idx - NPRE; int m = r / 576, k = r % 576, tap = k / 64, ci = k % 64;
        v = Wh0[(m * 64 + ci) * 9 + tap];
    } else if (idx < NPRE + N0 + N1) {
        int r = idx - NPRE - N0; int m = r / 864, k = r % 864, tap = k / 96, ci = k % 96;
        v = (ci < 64) ? Wx1[(m * 64 + ci) * 9 + tap] : Wh1[(m * 32 + (ci - 64)) * 9 + tap];
    } else {
        int r = idx - NPRE - N0 - N1; int m = r / 864, k = r % 864, tap = k / 96, ci = k % 96;
        v = (ci < 32) ? Wx2[(m * 32 + ci) * 9 + tap] : Wh2[(m * 64 + (ci - 32)) * 9 + tap];
    }
    A[idx] = (f16)v;
}

// x (B*T,192,784) f32 -> xT (B*T,784,192) f16, LDS-bounced transpose.
__global__ __launch_bounds__(256)
void transpose_x(const float* __restrict__ x, f16* __restrict__ xT)
{
    __shared__ float T[16 * 200];
    const int bt = blockIdx.y, p0 = blockIdx.x * 16;
    const int tid = threadIdx.x;
    const float* xb = x + (long)bt * 192 * NPIX;
#pragma unroll
    for (int it = 0; it < 12; ++it) {
        int idx = it * 256 + tid;
        int c = idx >> 4, p = idx & 15;
        T[p * 200 + c] = xb[c * NPIX + p0 + p];
    }
    __syncthreads();
    f16* dst = xT + ((long)bt * NPIX + p0) * 192;
#pragma unroll
    for (int it = 0; it < 12; ++it) {
        int idx = it * 256 + tid;
        int p = idx / 192, c = idx - p * 192;
        dst[p * 192 + c] = (f16)T[p * 200 + c];
    }
}

// Wp (3,HC,784) -> WpT (784,3,HC), per layer.
__global__ __launch_bounds__(256)
void transpose_wp(const float* __restrict__ Wp0, const float* __restrict__ Wp1,
                  const float* __restrict__ Wp2,
                  float* __restrict__ T0, float* __restrict__ T1, float* __restrict__ T2)
{
    const int N0 = NPIX * 192, N1 = NPIX * 96, N2 = NPIX * 192;
    int idx = blockIdx.x * 256 + threadIdx.x;
    if (idx < N0) {
        int pix = idx / 192, r = idx % 192;
        T0[idx] = Wp0[r * NPIX + pix];
    } else if (idx < N0 + N1) {
        int i = idx - N0; int pix = i / 96, r = i % 96;
        T1[i] = Wp1[r * NPIX + pix];
    } else if (idx < N0 + N1 + N2) {
        int i = idx - N0 - N1; int pix = i / 192, r = i % 192;
        T2[i] = Wp2[r * NPIX + pix];
    }
}

// h2 history f16 [17][b][pix][64] (slot t+1) -> out f32 (B,T,64,28,28)
__global__ __launch_bounds__(256)
void reshape_out(const f16* __restrict__ h2buf, float* __restrict__ out)
{
    int idx = blockIdx.x * 256 + threadIdx.x;
    int pix = idx % NPIX; int r = idx / NPIX;
    int hc = r & 63; r >>= 6;
    int t = r & 15; int b = r >> 4;
    out[idx] = (float)h2buf[((((long)(t + 1) * BB + b) * NPIX) + pix) * 64 + hc];
}

extern "C" void kernel_launch(void* const* d_in, const int* in_sizes, int n_in,
                              void* d_out, int out_size, void* d_ws, size_t ws_size,
                              hipStream_t stream)
{
    const float* x   = (const float*)d_in[0];
    const float* Wx0 = (const float*)d_in[1];
    const float* bx0 = (const float*)d_in[2];
    const float* Wh0 = (const float*)d_in[3];
    const float* Wp0 = (const float*)d_in[4];
    const float* Wx1 = (const float*)d_in[5];
    const float* bx1 = (const float*)d_in[6];
    const float* Wh1 = (const float*)d_in[7];
    const float* Wp1 = (const float*)d_in[8];
    const float* Wx2 = (const float*)d_in[9];
    const float* bx2 = (const float*)d_in[10];
    const float* Wh2 = (const float*)d_in[11];
    const float* Wp2 = (const float*)d_in[12];
    (void)in_sizes; (void)n_in; (void)out_size; (void)ws_size;

    char* w = (char*)d_ws;
    f16* Apack = (f16*)w;                                   // 1,843,200 B
    f16* Apre  = Apack;
    f16* Ap0   = Apre + 256L * 1728;
    f16* Ap1   = Ap0  + 256L * 576;
    f16* Ap2   = Ap1  + 128L * 864;
    f16* xT    = (f16*)(w + 1843200);                       // 38,535,168 B
    f16* gx    = (f16*)(w + 40378368);                      // 51,380,224 B
    float* c0  = (float*)(w + 91758592);                    // 1,605,632 B
    float* c1  = c0 + (long)BB * NPIX * 64;                 //   802,816 B
    float* c2  = c1 + (long)BB * NPIX * 32;                 // 1,605,632 B
    f16* h0    = (f16*)(c2 + (long)BB * NPIX * 64);         // 2x  802,816 B
    f16* h1    = h0 + 2L * BB * NPIX * 64;                  // 2x  401,408 B
    f16* h2buf = h1 + 2L * BB * NPIX * 32;                  // 17x 802,816 B
    float* WpT0 = (float*)(w + 111828992);                  //   602,112 B
    float* WpT1 = WpT0 + (long)NPIX * 192;                  //   301,056 B
    float* WpT2 = WpT1 + (long)NPIX * 96;                   //   602,112 B

    // zero c0..h1 + h2 slot 0 (contiguous: 7,225,344 B from c0)
    hipMemsetAsync(c0, 0, (size_t)7225344, stream);

    pack_weights<<<3600, 256, 0, stream>>>(Wx0, Wh0, Wx1, Wh1, Wx2, Wh2, Apack);
    transpose_x<<<dim3(49, BB * TT), 256, 0, stream>>>(x, xT);
    transpose_wp<<<1470, 256, 0, stream>>>(Wp0, Wp1, Wp2, WpT0, WpT1, WpT2);

    // time-parallel layer-0 input conv for all B*T images (4x28 strips, M/2)
    conv_pre_kernel<<<dim3(14, BB * TT), 256, 0, stream>>>(xT, Apre, gx);

    // diagonal wavefront: one launch runs L0(t=d), L1(d-1), L2(d-2)
    for (int d = 0; d < TT + 2; ++d) {
        diag_kernel<<<dim3(28, BB, 3), 256, 0, stream>>>(d,
            Ap0, Ap1, Ap2, gx, bx0, bx1, bx2,
            WpT0, WpT1, WpT2, c0, c1, c2, h0, h1, h2buf);
    }

    reshape_out<<<25088, 256, 0, stream>>>(h2buf, (float*)d_out);
}